// Round 19
// baseline (144.233 us; speedup 1.0000x reference)
//
#include <hip/hip_runtime.h>

#define DD 128
#define D2 64        // DD/2 packed-uint columns
#define BW_DST 32
#define BW_SHIFT 5
#define BATCH 4096
#define NBPAD 320    // >= ceil(N/32) = 313; = 64*5 for the wave scan
#define CAP 4096     // fixed per-bucket region in bcsr (avg bucket ~2045, max ~2300)
#define P2CAP 6144   // fine_sort LDS capacity (uint recs per bucket)

__device__ __forceinline__ unsigned int bf16rne(float f) {
    unsigned int u = __float_as_uint(f);
    unsigned int r = ((u >> 16) & 1u) + 0x7fffu;   // round-to-nearest-even
    return (u + r) >> 16;
}
__device__ __forceinline__ float bflo(unsigned int v) { return __uint_as_float(v << 16); }
__device__ __forceinline__ float bfhi(unsigned int v) { return __uint_as_float(v & 0xFFFF0000u); }

// init per-bucket cursors to region starts; zero the completion ticket
__global__ void init_bcur(int* __restrict__ bcur, int* __restrict__ ticket) {
    bcur[threadIdx.x] = (int)threadIdx.x * CAP;   // <<<1, NBPAD>>>
    if (threadIdx.x == 0) *ticket = 0;
}

// Heterogeneous grid: blocks [0,nfill) = single-pass bucket sort; the LAST
// fill block to finish also runs the bucket-base scan (ticket pattern —
// scan reads only device-scope-atomic bcur).  Blocks [nfill,..) = layer-0 GEMM.
__global__ __launch_bounds__(256) void fill_and_gemm0(
    const int* __restrict__ src, const int* __restrict__ dst, int E,
    int* __restrict__ bcur, unsigned int* __restrict__ bcsr, int NB, int nfill,
    const float* __restrict__ x, const float* __restrict__ W,
    unsigned int* __restrict__ xwb, int N,
    int* __restrict__ ticket, int* __restrict__ bbase, int* __restrict__ row_ptr)
{
    union SM {
        struct {
            unsigned short sbkt[BATCH];
            unsigned short sbkt2[BATCH];
            int cnt[NBPAD];
            int boff[NBPAD];
            int gbase[NBPAD];
            int lcur[NBPAD];
            unsigned int staged[BATCH];
        } f;
        float xs[16][DD];
        int part[256];
    };
    __shared__ SM sm;
    __shared__ int is_last;
    int t = threadIdx.x;

    if ((int)blockIdx.x < nfill) {
        for (int base = blockIdx.x * BATCH; base < E; base += nfill * BATCH) {
            int n = min(E - base, BATCH);
            for (int b = t; b < NBPAD; b += 256) sm.f.cnt[b] = 0;
            __syncthreads();
            for (int i = t; i < n; i += 256) {
                int d = dst[base + i];
                int bk = d >> BW_SHIFT;
                sm.f.sbkt[i] = (unsigned short)bk;
                atomicAdd(&sm.f.cnt[bk], 1);
            }
            __syncthreads();
            if (t < 64) {
                int lo = t * 5;
                int c0 = sm.f.cnt[lo], c1 = sm.f.cnt[lo + 1], c2 = sm.f.cnt[lo + 2],
                    c3 = sm.f.cnt[lo + 3], c4 = sm.f.cnt[lo + 4];
                int s = c0 + c1 + c2 + c3 + c4;
                int v = s;
                #pragma unroll
                for (int o = 1; o < 64; o <<= 1) { int u = __shfl_up(v, o, 64); if (t >= o) v += u; }
                int e0 = v - s;
                int e1 = e0 + c0, e2 = e1 + c1, e3 = e2 + c2, e4 = e3 + c3;
                sm.f.boff[lo] = e0; sm.f.boff[lo + 1] = e1; sm.f.boff[lo + 2] = e2;
                sm.f.boff[lo + 3] = e3; sm.f.boff[lo + 4] = e4;
                sm.f.lcur[lo] = e0; sm.f.lcur[lo + 1] = e1; sm.f.lcur[lo + 2] = e2;
                sm.f.lcur[lo + 3] = e3; sm.f.lcur[lo + 4] = e4;
                if (c0) sm.f.gbase[lo]     = atomicAdd(&bcur[lo],     c0);
                if (c1) sm.f.gbase[lo + 1] = atomicAdd(&bcur[lo + 1], c1);
                if (c2) sm.f.gbase[lo + 2] = atomicAdd(&bcur[lo + 2], c2);
                if (c3) sm.f.gbase[lo + 3] = atomicAdd(&bcur[lo + 3], c3);
                if (c4) sm.f.gbase[lo + 4] = atomicAdd(&bcur[lo + 4], c4);
            }
            __syncthreads();
            for (int i = t; i < n; i += 256) {
                int e = base + i;
                int ss = src[e], dd = dst[e];
                int bk = sm.f.sbkt[i];
                int p = atomicAdd(&sm.f.lcur[bk], 1);
                sm.f.staged[p] = (unsigned int)ss | ((unsigned int)(dd & (BW_DST - 1)) << 27);
                sm.f.sbkt2[p] = (unsigned short)bk;
            }
            __syncthreads();
            for (int i = t; i < n; i += 256) {
                int bk = sm.f.sbkt2[i];
                bcsr[sm.f.gbase[bk] + (i - sm.f.boff[bk])] = sm.f.staged[i];
            }
            __syncthreads();
        }
        // ---- ticket: last fill block runs the bucket-base scan ----
        if (t == 0) {
            __threadfence();
            int done = atomicAdd(ticket, 1);
            is_last = (done == nfill - 1);
        }
        __syncthreads();
        if (is_last) {
            int chunk = (NB + 255) / 256;
            int lo = t * chunk, hi = min(lo + chunk, NB);
            int s = 0;
            for (int b = lo; b < hi; ++b) s += bcur[b] - b * CAP;
            sm.part[t] = s;
            __syncthreads();
            for (int o = 1; o < 256; o <<= 1) {
                int v = (t >= o) ? sm.part[t - o] : 0;
                __syncthreads();
                sm.part[t] += v;
                __syncthreads();
            }
            int run = (t == 0) ? 0 : sm.part[t - 1];
            for (int b = lo; b < hi; ++b) {
                bbase[b] = run;
                run += bcur[b] - b * CAP;
            }
            if (t == 0) row_ptr[N] = E;
        }
        return;
    }
    // ---- gemm0 part: 16 rows per block, 256 threads ----
    int r0 = ((int)blockIdx.x - nfill) * 16;
    for (int j = t; j < 16 * DD; j += 256) {
        int r = j >> 7, c2 = j & 127;
        int row = r0 + r;
        sm.xs[r][c2] = (row < N) ? x[row * DD + c2] : 0.f;
    }
    __syncthreads();
    int col = t & 127, h = t >> 7;
    float acc[8];
    #pragma unroll
    for (int r = 0; r < 8; ++r) acc[r] = 0.f;
    for (int k = 0; k < DD; k += 4) {
        float w0 = W[(k + 0) * DD + col];
        float w1 = W[(k + 1) * DD + col];
        float w2 = W[(k + 2) * DD + col];
        float w3 = W[(k + 3) * DD + col];
        #pragma unroll
        for (int r = 0; r < 8; ++r) {
            float4 xv = *(const float4*)&sm.xs[h * 8 + r][k];
            acc[r] = fmaf(xv.x, w0, acc[r]);
            acc[r] = fmaf(xv.y, w1, acc[r]);
            acc[r] = fmaf(xv.z, w2, acc[r]);
            acc[r] = fmaf(xv.w, w3, acc[r]);
        }
    }
    #pragma unroll
    for (int r = 0; r < 8; ++r) {
        int row = r0 + h * 8 + r;
        float other = __shfl_xor(acc[r], 1);
        if (row < N && !(t & 1)) {
            unsigned int p = bf16rne(acc[r]) | (bf16rne(other) << 16);
            xwb[row * D2 + (col >> 1)] = p;
        }
    }
}

// Per bucket: derive degree/dinv/row_ptr from LDS hist, fine-sort by dst,
// write 4 B recs at the global CSR base (dl bits KEPT for the agg kernels).
__global__ __launch_bounds__(256) void fine_sort(
    const int* __restrict__ bcur, const int* __restrict__ bbase,
    const unsigned int* __restrict__ bcsr,
    unsigned int* __restrict__ csr4, int* __restrict__ row_ptr,
    float* __restrict__ dinv, int N, int NB, int E)
{
    __shared__ unsigned int staged[P2CAP];
    __shared__ int dcnt[BW_DST];
    __shared__ int dcur[BW_DST];
    int b = blockIdx.x;
    int d0 = b << BW_SHIFT;
    int nd = min(BW_DST, N - d0);
    int base_in = b * CAP;
    int cnt = bcur[b] - base_in;
    int gout = bbase[b];
    int t = threadIdx.x;
    if (t < BW_DST) dcnt[t] = 0;
    __syncthreads();
    for (int i = t; i < cnt; i += 256) atomicAdd(&dcnt[bcsr[base_in + i] >> 27], 1);
    __syncthreads();
    if (t < BW_DST) {
        int c = dcnt[t];
        int v = c;
        #pragma unroll
        for (int o = 1; o < BW_DST; o <<= 1) { int u = __shfl_up(v, o, BW_DST); if (t >= o) v += u; }
        int loff = v - c;
        if (t < nd) {
            int node = d0 + t;
            row_ptr[node] = gout + loff;
            dinv[node] = rsqrtf((float)(c + 1));   // + self-loop
        }
        dcur[t] = loff;
    }
    __syncthreads();
    if (cnt <= P2CAP) {
        for (int i = t; i < cnt; i += 256) {
            unsigned int r = bcsr[base_in + i];
            int p = atomicAdd(&dcur[r >> 27], 1);
            staged[p] = r;
        }
        __syncthreads();
        for (int i = t; i < cnt; i += 256) csr4[gout + i] = staged[i];
    } else {
        for (int i = t; i < cnt; i += 256) {
            unsigned int r = bcsr[base_in + i];
            int p = atomicAdd(&dcur[r >> 27], 1);
            csr4[gout + p] = r;
        }
    }
}

// ---- agg kernels (byte-identical to R17/R18-proven) ----
// result = dinv[d] * ( sum_e dinv[s]*row[s] + dinv[d]*row[d] ) + bias

__global__ __launch_bounds__(512) void agg_gemm(
    const unsigned int* __restrict__ xwb_in, const unsigned int* __restrict__ csr,
    const int* __restrict__ row_ptr, const float* __restrict__ dinv,
    const float* __restrict__ bias, const float* __restrict__ gamma,
    const float* __restrict__ beta, const float* __restrict__ W,
    unsigned int* __restrict__ xwb_out, int N)
{
    __shared__ float xs[8][DD];
    int t = threadIdx.x;
    int wid = t >> 6, l = t & 63;
    int i = blockIdx.x * 8 + wid;
    if (i < N) {
        int beg = row_ptr[i], end = row_ptr[i + 1];
        float ax = 0.f, ay = 0.f;
        #pragma unroll 16
        for (int j = beg; j < end; ++j) {
            unsigned int r = csr[j];            // wave-uniform -> scalar load
            unsigned int s = r & 0x07FFFFFFu;
            float dvs = dinv[s];                // wave-uniform 4 B (L1/L2)
            unsigned int v = xwb_in[s * D2 + l];
            ax = fmaf(bflo(v), dvs, ax);
            ay = fmaf(bfhi(v), dvs, ay);
        }
        float di = dinv[i];
        unsigned int v = xwb_in[i * D2 + l];
        ax = fmaf(bflo(v), di, ax);             // self-loop (inner factor)
        ay = fmaf(bfhi(v), di, ay);
        float2 b2 = ((const float2*)bias)[l];
        ax = fmaf(ax, di, b2.x);                // apply dinv[d] + bias
        ay = fmaf(ay, di, b2.y);
        float sum = ax + ay, sq = ax * ax + ay * ay;
        #pragma unroll
        for (int o = 32; o > 0; o >>= 1) { sum += __shfl_xor(sum, o); sq += __shfl_xor(sq, o); }
        float mu   = sum * (1.f / DD);
        float var  = sq * (1.f / DD) - mu * mu;
        float rstd = rsqrtf(var + 1e-5f);
        float2 g2  = ((const float2*)gamma)[l];
        float2 be2 = ((const float2*)beta)[l];
        float y0 = (ax - mu) * rstd * g2.x + be2.x;
        float y1 = (ay - mu) * rstd * g2.y + be2.y;
        y0 = 0.5f * y0 * (1.f + tanhf(0.7978845608f * (y0 + 0.044715f * y0 * y0 * y0)));
        y1 = 0.5f * y1 * (1.f + tanhf(0.7978845608f * (y1 + 0.044715f * y1 * y1 * y1)));
        xs[wid][2 * l]     = y0;
        xs[wid][2 * l + 1] = y1;
    } else {
        xs[wid][2 * l]     = 0.f;
        xs[wid][2 * l + 1] = 0.f;
    }
    __syncthreads();
    int col = t & 127, h = t >> 7;   // h -> rows 2h, 2h+1
    float a0 = 0.f, a1 = 0.f;
    for (int k = 0; k < DD; k += 4) {
        float w0 = W[(k + 0) * DD + col];
        float w1 = W[(k + 1) * DD + col];
        float w2 = W[(k + 2) * DD + col];
        float w3 = W[(k + 3) * DD + col];
        float4 x0 = *(const float4*)&xs[h * 2 + 0][k];
        float4 x1 = *(const float4*)&xs[h * 2 + 1][k];
        a0 = fmaf(x0.x, w0, a0); a0 = fmaf(x0.y, w1, a0);
        a0 = fmaf(x0.z, w2, a0); a0 = fmaf(x0.w, w3, a0);
        a1 = fmaf(x1.x, w0, a1); a1 = fmaf(x1.y, w1, a1);
        a1 = fmaf(x1.z, w2, a1); a1 = fmaf(x1.w, w3, a1);
    }
    int row0 = blockIdx.x * 8 + h * 2;
    float o0 = __shfl_xor(a0, 1);
    float o1 = __shfl_xor(a1, 1);
    if (!(t & 1)) {
        if (row0 < N)
            xwb_out[row0 * D2 + (col >> 1)] = bf16rne(a0) | (bf16rne(o0) << 16);
        if (row0 + 1 < N)
            xwb_out[(row0 + 1) * D2 + (col >> 1)] = bf16rne(a1) | (bf16rne(o1) << 16);
    }
}

// Final layer: 4 waves/block, one node per wave.
__global__ __launch_bounds__(256) void agg_ln_gelu(
    const unsigned int* __restrict__ xwb, const unsigned int* __restrict__ csr,
    const int* __restrict__ row_ptr, const float* __restrict__ dinv,
    const float* __restrict__ bias, const float* __restrict__ gamma,
    const float* __restrict__ beta, float* __restrict__ out, int N)
{
    int i = blockIdx.x * 4 + (threadIdx.x >> 6);
    if (i >= N) return;
    int l = threadIdx.x & 63;
    int beg = row_ptr[i], end = row_ptr[i + 1];
    float ax = 0.f, ay = 0.f;
    #pragma unroll 16
    for (int j = beg; j < end; ++j) {
        unsigned int r = csr[j];
        unsigned int s = r & 0x07FFFFFFu;
        float dvs = dinv[s];
        unsigned int v = xwb[s * D2 + l];
        ax = fmaf(bflo(v), dvs, ax);
        ay = fmaf(bfhi(v), dvs, ay);
    }
    float di = dinv[i];
    unsigned int v = xwb[i * D2 + l];
    ax = fmaf(bflo(v), di, ax);
    ay = fmaf(bfhi(v), di, ay);
    float2 b2 = ((const float2*)bias)[l];
    ax = fmaf(ax, di, b2.x);
    ay = fmaf(ay, di, b2.y);
    float sum = ax + ay, sq = ax * ax + ay * ay;
    #pragma unroll
    for (int o = 32; o > 0; o >>= 1) { sum += __shfl_xor(sum, o); sq += __shfl_xor(sq, o); }
    float mu   = sum * (1.f / DD);
    float var  = sq * (1.f / DD) - mu * mu;
    float rstd = rsqrtf(var + 1e-5f);
    float2 g2  = ((const float2*)gamma)[l];
    float2 be2 = ((const float2*)beta)[l];
    float y0 = (ax - mu) * rstd * g2.x + be2.x;
    float y1 = (ay - mu) * rstd * g2.y + be2.y;
    y0 = 0.5f * y0 * (1.f + tanhf(0.7978845608f * (y0 + 0.044715f * y0 * y0 * y0)));
    y1 = 0.5f * y1 * (1.f + tanhf(0.7978845608f * (y1 + 0.044715f * y1 * y1 * y1)));
    float2 o2; o2.x = y0; o2.y = y1;
    ((float2*)out)[i * D2 + l] = o2;
}

static inline size_t align_up(size_t x, size_t a) { return (x + a - 1) & ~(a - 1); }

extern "C" void kernel_launch(void* const* d_in, const int* in_sizes, int n_in,
                              void* d_out, int out_size, void* d_ws, size_t ws_size,
                              hipStream_t stream) {
    const float* z      = (const float*)d_in[0];
    const int*   ei     = (const int*)d_in[1];
    const float* Ws     = (const float*)d_in[2];
    const float* bs     = (const float*)d_in[3];
    const float* gammas = (const float*)d_in[4];
    const float* betas  = (const float*)d_in[5];

    int E  = in_sizes[1] / 2;
    int LD = in_sizes[3];
    int Dd = in_sizes[2] / LD;            // 128
    int L  = LD / Dd;
    int N  = in_sizes[0] / Dd;
    int NB = (N + BW_DST - 1) / BW_DST;   // 313

    const int* srcp = ei;
    const int* dstp = ei + E;

    char* ws = (char*)d_ws;
    size_t off = 0;
    int* bcur = (int*)(ws + off);        off = align_up(off + (size_t)NBPAD * 4, 256);
    int* bbase = (int*)(ws + off);       off = align_up(off + (size_t)NBPAD * 4, 256);
    int* ticket = (int*)(ws + off);      off = align_up(off + 4, 256);
    float* dinv = (float*)(ws + off);    off = align_up(off + (size_t)N * 4, 256);
    int* row_ptr = (int*)(ws + off);     off = align_up(off + (size_t)(N + 1) * 4, 256);
    unsigned int* bcsr = (unsigned int*)(ws + off); off = align_up(off + (size_t)NBPAD * CAP * 4, 256);
    unsigned int* csr4 = (unsigned int*)(ws + off); off = align_up(off + (size_t)E * 4, 256);
    unsigned int* xwb_a = (unsigned int*)(ws + off); off = align_up(off + (size_t)N * D2 * 4, 256);
    unsigned int* xwb_b = (unsigned int*)(ws + off); off = align_up(off + (size_t)N * D2 * 4, 256);
    float* dout = (float*)d_out;
    (void)ws_size; (void)n_in; (void)out_size;

    int nfill = (E + BATCH - 1) / BATCH;   // 157
    int nb_gemm = (N + 15) / 16;           // 625

    init_bcur<<<1, NBPAD, 0, stream>>>(bcur, ticket);
    fill_and_gemm0<<<nfill + nb_gemm, 256, 0, stream>>>(
        srcp, dstp, E, bcur, bcsr, NB, nfill, z, Ws, xwb_a, N,
        ticket, bbase, row_ptr);
    fine_sort<<<NB, 256, 0, stream>>>(bcur, bbase, bcsr, csr4, row_ptr, dinv, N, NB, E);

    // middle layers: fused agg(li)+LN+gelu -> GEMM W(li+1)
    unsigned int* tin = xwb_a;
    unsigned int* tout = xwb_b;
    for (int li = 0; li < L - 1; ++li) {
        agg_gemm<<<(N + 7) / 8, 512, 0, stream>>>(
            tin, csr4, row_ptr, dinv,
            bs + (size_t)li * Dd, gammas + (size_t)li * Dd, betas + (size_t)li * Dd,
            Ws + (size_t)(li + 1) * Dd * Dd, tout, N);
        unsigned int* tmp = tin; tin = tout; tout = tmp;
    }

    // final layer: agg + LN + gelu -> f32 out
    agg_ln_gelu<<<(N + 3) / 4, 256, 0, stream>>>(tin, csr4, row_ptr, dinv,
                                                 bs + (size_t)(L - 1) * Dd,
                                                 gammas + (size_t)(L - 1) * Dd,
                                                 betas + (size_t)(L - 1) * Dd, dout, N);
}

// Round 20
// 141.117 us; speedup vs baseline: 1.0221x; 1.0221x over previous
//
#include <hip/hip_runtime.h>

#define DD 128
#define D2 64        // DD/2 packed-uint columns
#define BW_DST 32
#define BW_SHIFT 5
#define BATCH 4096
#define NBPAD 320    // >= ceil(N/32) = 313; = 64*5 for the wave scan
#define CAP 4096     // fixed per-bucket region in bcsr (avg bucket ~2045, max ~2300)
#define P2CAP 6144   // fine_sort LDS capacity (uint recs per bucket)

__device__ __forceinline__ unsigned int bf16rne(float f) {
    unsigned int u = __float_as_uint(f);
    unsigned int r = ((u >> 16) & 1u) + 0x7fffu;   // round-to-nearest-even
    return (u + r) >> 16;
}
__device__ __forceinline__ float bflo(unsigned int v) { return __uint_as_float(v << 16); }
__device__ __forceinline__ float bfhi(unsigned int v) { return __uint_as_float(v & 0xFFFF0000u); }

// init per-bucket cursors to the start of their fixed regions
__global__ void init_bcur(int* __restrict__ bcur) {
    bcur[threadIdx.x] = (int)threadIdx.x * CAP;   // <<<1, NBPAD>>>
}

// Heterogeneous grid: blocks [0,nfill) = single-pass bucket sort (fixed-CAP,
// BATCH=4096); blocks [nfill, nfill+nb_gemm) = layer-0 GEMM.  gemm0 hides
// under the fill.  (R18-proven, 140.9 us)
__global__ __launch_bounds__(256) void fill_and_gemm0(
    const int* __restrict__ src, const int* __restrict__ dst, int E,
    int* __restrict__ bcur, unsigned int* __restrict__ bcsr, int NB, int nfill,
    const float* __restrict__ x, const float* __restrict__ W,
    unsigned int* __restrict__ xwb, int N)
{
    union SM {
        struct {
            unsigned short sbkt[BATCH];       // 8 KB  bucket of input idx
            unsigned short sbkt2[BATCH];      // 8 KB  bucket of sorted pos
            int cnt[NBPAD];
            int boff[NBPAD];
            int gbase[NBPAD];
            int lcur[NBPAD];
            unsigned int staged[BATCH];       // 16 KB
        } f;
        float xs[16][DD];                     // 8 KB
    };
    __shared__ SM sm;
    int t = threadIdx.x;

    if ((int)blockIdx.x < nfill) {
        for (int base = blockIdx.x * BATCH; base < E; base += nfill * BATCH) {
            int n = min(E - base, BATCH);
            for (int b = t; b < NBPAD; b += 256) sm.f.cnt[b] = 0;   // pad-zero
            __syncthreads();
            for (int i = t; i < n; i += 256) {
                int d = dst[base + i];
                int bk = d >> BW_SHIFT;
                sm.f.sbkt[i] = (unsigned short)bk;
                atomicAdd(&sm.f.cnt[bk], 1);
            }
            __syncthreads();
            if (t < 64) {
                int lo = t * 5;
                int c0 = sm.f.cnt[lo], c1 = sm.f.cnt[lo + 1], c2 = sm.f.cnt[lo + 2],
                    c3 = sm.f.cnt[lo + 3], c4 = sm.f.cnt[lo + 4];
                int s = c0 + c1 + c2 + c3 + c4;
                int v = s;
                #pragma unroll
                for (int o = 1; o < 64; o <<= 1) { int u = __shfl_up(v, o, 64); if (t >= o) v += u; }
                int e0 = v - s;
                int e1 = e0 + c0, e2 = e1 + c1, e3 = e2 + c2, e4 = e3 + c3;
                sm.f.boff[lo] = e0; sm.f.boff[lo + 1] = e1; sm.f.boff[lo + 2] = e2;
                sm.f.boff[lo + 3] = e3; sm.f.boff[lo + 4] = e4;
                sm.f.lcur[lo] = e0; sm.f.lcur[lo + 1] = e1; sm.f.lcur[lo + 2] = e2;
                sm.f.lcur[lo + 3] = e3; sm.f.lcur[lo + 4] = e4;
                if (c0) sm.f.gbase[lo]     = atomicAdd(&bcur[lo],     c0);
                if (c1) sm.f.gbase[lo + 1] = atomicAdd(&bcur[lo + 1], c1);
                if (c2) sm.f.gbase[lo + 2] = atomicAdd(&bcur[lo + 2], c2);
                if (c3) sm.f.gbase[lo + 3] = atomicAdd(&bcur[lo + 3], c3);
                if (c4) sm.f.gbase[lo + 4] = atomicAdd(&bcur[lo + 4], c4);
            }
            __syncthreads();
            for (int i = t; i < n; i += 256) {
                int e = base + i;
                int ss = src[e], dd = dst[e];
                int bk = sm.f.sbkt[i];
                int p = atomicAdd(&sm.f.lcur[bk], 1);
                sm.f.staged[p] = (unsigned int)ss | ((unsigned int)(dd & (BW_DST - 1)) << 27);
                sm.f.sbkt2[p] = (unsigned short)bk;
            }
            __syncthreads();
            // sorted strided flush: consecutive i -> consecutive global addr per run
            for (int i = t; i < n; i += 256) {
                int bk = sm.f.sbkt2[i];
                bcsr[sm.f.gbase[bk] + (i - sm.f.boff[bk])] = sm.f.staged[i];
            }
            __syncthreads();
        }
        return;
    }
    // ---- gemm0 part: 16 rows per block, 256 threads ----
    int r0 = ((int)blockIdx.x - nfill) * 16;
    for (int j = t; j < 16 * DD; j += 256) {
        int r = j >> 7, c2 = j & 127;
        int row = r0 + r;
        sm.xs[r][c2] = (row < N) ? x[row * DD + c2] : 0.f;
    }
    __syncthreads();
    int col = t & 127, h = t >> 7;
    float acc[8];
    #pragma unroll
    for (int r = 0; r < 8; ++r) acc[r] = 0.f;
    for (int k = 0; k < DD; k += 4) {
        float w0 = W[(k + 0) * DD + col];
        float w1 = W[(k + 1) * DD + col];
        float w2 = W[(k + 2) * DD + col];
        float w3 = W[(k + 3) * DD + col];
        #pragma unroll
        for (int r = 0; r < 8; ++r) {
            float4 xv = *(const float4*)&sm.xs[h * 8 + r][k];
            acc[r] = fmaf(xv.x, w0, acc[r]);
            acc[r] = fmaf(xv.y, w1, acc[r]);
            acc[r] = fmaf(xv.z, w2, acc[r]);
            acc[r] = fmaf(xv.w, w3, acc[r]);
        }
    }
    #pragma unroll
    for (int r = 0; r < 8; ++r) {
        int row = r0 + h * 8 + r;
        float other = __shfl_xor(acc[r], 1);
        if (row < N && !(t & 1)) {
            unsigned int p = bf16rne(acc[r]) | (bf16rne(other) << 16);
            xwb[row * D2 + (col >> 1)] = p;
        }
    }
}

// Single block: bucket counts from cursors -> exclusive scan -> global CSR bases.
__global__ void scan_cnt(const int* __restrict__ bcur, int* __restrict__ bbase,
                         int* __restrict__ row_ptr, int NB, int N, int E)
{
    __shared__ int part[256];
    int t = threadIdx.x;
    int chunk = (NB + 255) / 256;
    int lo = t * chunk, hi = min(lo + chunk, NB);
    int s = 0;
    for (int b = lo; b < hi; ++b) s += bcur[b] - b * CAP;
    part[t] = s;
    __syncthreads();
    for (int o = 1; o < 256; o <<= 1) {
        int v = (t >= o) ? part[t - o] : 0;
        __syncthreads();
        part[t] += v;
        __syncthreads();
    }
    int run = (t == 0) ? 0 : part[t - 1];
    for (int b = lo; b < hi; ++b) {
        bbase[b] = run;
        run += bcur[b] - b * CAP;
    }
    if (t == 0) row_ptr[N] = E;
}

// Per bucket: derive degree/dinv/row_ptr from LDS hist, fine-sort by dst,
// write 4 B recs at the global CSR base (dl bits KEPT for the agg kernels).
__global__ __launch_bounds__(256) void fine_sort(
    const int* __restrict__ bcur, const int* __restrict__ bbase,
    const unsigned int* __restrict__ bcsr,
    unsigned int* __restrict__ csr4, int* __restrict__ row_ptr,
    float* __restrict__ dinv, int N, int NB, int E)
{
    __shared__ unsigned int staged[P2CAP];
    __shared__ int dcnt[BW_DST];
    __shared__ int dcur[BW_DST];
    int b = blockIdx.x;
    int d0 = b << BW_SHIFT;
    int nd = min(BW_DST, N - d0);
    int base_in = b * CAP;
    int cnt = bcur[b] - base_in;
    int gout = bbase[b];
    int t = threadIdx.x;
    if (t < BW_DST) dcnt[t] = 0;
    __syncthreads();
    for (int i = t; i < cnt; i += 256) atomicAdd(&dcnt[bcsr[base_in + i] >> 27], 1);
    __syncthreads();
    if (t < BW_DST) {
        int c = dcnt[t];
        int v = c;
        #pragma unroll
        for (int o = 1; o < BW_DST; o <<= 1) { int u = __shfl_up(v, o, BW_DST); if (t >= o) v += u; }
        int loff = v - c;
        if (t < nd) {
            int node = d0 + t;
            row_ptr[node] = gout + loff;
            dinv[node] = rsqrtf((float)(c + 1));   // + self-loop
        }
        dcur[t] = loff;
    }
    __syncthreads();
    if (cnt <= P2CAP) {
        for (int i = t; i < cnt; i += 256) {
            unsigned int r = bcsr[base_in + i];
            int p = atomicAdd(&dcur[r >> 27], 1);
            staged[p] = r;
        }
        __syncthreads();
        for (int i = t; i < cnt; i += 256) csr4[gout + i] = staged[i];
    } else {
        for (int i = t; i < cnt; i += 256) {
            unsigned int r = bcsr[base_in + i];
            int p = atomicAdd(&dcur[r >> 27], 1);
            csr4[gout + p] = r;
        }
    }
}

// ---- agg kernels (R17-proven) ----
// result = dinv[d] * ( sum_e dinv[s]*row[s] + dinv[d]*row[d] ) + bias

__global__ __launch_bounds__(512) void agg_gemm(
    const unsigned int* __restrict__ xwb_in, const unsigned int* __restrict__ csr,
    const int* __restrict__ row_ptr, const float* __restrict__ dinv,
    const float* __restrict__ bias, const float* __restrict__ gamma,
    const float* __restrict__ beta, const float* __restrict__ W,
    unsigned int* __restrict__ xwb_out, int N)
{
    __shared__ float xs[8][DD];
    int t = threadIdx.x;
    int wid = t >> 6, l = t & 63;
    int i = blockIdx.x * 8 + wid;
    if (i < N) {
        int beg = row_ptr[i], end = row_ptr[i + 1];
        float ax = 0.f, ay = 0.f;
        #pragma unroll 16
        for (int j = beg; j < end; ++j) {
            unsigned int r = csr[j];            // wave-uniform -> scalar load
            unsigned int s = r & 0x07FFFFFFu;
            float dvs = dinv[s];                // wave-uniform 4 B (L1/L2)
            unsigned int v = xwb_in[s * D2 + l];
            ax = fmaf(bflo(v), dvs, ax);
            ay = fmaf(bfhi(v), dvs, ay);
        }
        float di = dinv[i];
        unsigned int v = xwb_in[i * D2 + l];
        ax = fmaf(bflo(v), di, ax);             // self-loop (inner factor)
        ay = fmaf(bfhi(v), di, ay);
        float2 b2 = ((const float2*)bias)[l];
        ax = fmaf(ax, di, b2.x);                // apply dinv[d] + bias
        ay = fmaf(ay, di, b2.y);
        float sum = ax + ay, sq = ax * ax + ay * ay;
        #pragma unroll
        for (int o = 32; o > 0; o >>= 1) { sum += __shfl_xor(sum, o); sq += __shfl_xor(sq, o); }
        float mu   = sum * (1.f / DD);
        float var  = sq * (1.f / DD) - mu * mu;
        float rstd = rsqrtf(var + 1e-5f);
        float2 g2  = ((const float2*)gamma)[l];
        float2 be2 = ((const float2*)beta)[l];
        float y0 = (ax - mu) * rstd * g2.x + be2.x;
        float y1 = (ay - mu) * rstd * g2.y + be2.y;
        y0 = 0.5f * y0 * (1.f + tanhf(0.7978845608f * (y0 + 0.044715f * y0 * y0 * y0)));
        y1 = 0.5f * y1 * (1.f + tanhf(0.7978845608f * (y1 + 0.044715f * y1 * y1 * y1)));
        xs[wid][2 * l]     = y0;
        xs[wid][2 * l + 1] = y1;
    } else {
        xs[wid][2 * l]     = 0.f;
        xs[wid][2 * l + 1] = 0.f;
    }
    __syncthreads();
    int col = t & 127, h = t >> 7;   // h -> rows 2h, 2h+1
    float a0 = 0.f, a1 = 0.f;
    for (int k = 0; k < DD; k += 4) {
        float w0 = W[(k + 0) * DD + col];
        float w1 = W[(k + 1) * DD + col];
        float w2 = W[(k + 2) * DD + col];
        float w3 = W[(k + 3) * DD + col];
        float4 x0 = *(const float4*)&xs[h * 2 + 0][k];
        float4 x1 = *(const float4*)&xs[h * 2 + 1][k];
        a0 = fmaf(x0.x, w0, a0); a0 = fmaf(x0.y, w1, a0);
        a0 = fmaf(x0.z, w2, a0); a0 = fmaf(x0.w, w3, a0);
        a1 = fmaf(x1.x, w0, a1); a1 = fmaf(x1.y, w1, a1);
        a1 = fmaf(x1.z, w2, a1); a1 = fmaf(x1.w, w3, a1);
    }
    int row0 = blockIdx.x * 8 + h * 2;
    float o0 = __shfl_xor(a0, 1);
    float o1 = __shfl_xor(a1, 1);
    if (!(t & 1)) {
        if (row0 < N)
            xwb_out[row0 * D2 + (col >> 1)] = bf16rne(a0) | (bf16rne(o0) << 16);
        if (row0 + 1 < N)
            xwb_out[(row0 + 1) * D2 + (col >> 1)] = bf16rne(a1) | (bf16rne(o1) << 16);
    }
}

// Final layer: 4 waves/block, one node per wave.
__global__ __launch_bounds__(256) void agg_ln_gelu(
    const unsigned int* __restrict__ xwb, const unsigned int* __restrict__ csr,
    const int* __restrict__ row_ptr, const float* __restrict__ dinv,
    const float* __restrict__ bias, const float* __restrict__ gamma,
    const float* __restrict__ beta, float* __restrict__ out, int N)
{
    int i = blockIdx.x * 4 + (threadIdx.x >> 6);
    if (i >= N) return;
    int l = threadIdx.x & 63;
    int beg = row_ptr[i], end = row_ptr[i + 1];
    float ax = 0.f, ay = 0.f;
    #pragma unroll 16
    for (int j = beg; j < end; ++j) {
        unsigned int r = csr[j];
        unsigned int s = r & 0x07FFFFFFu;
        float dvs = dinv[s];
        unsigned int v = xwb[s * D2 + l];
        ax = fmaf(bflo(v), dvs, ax);
        ay = fmaf(bfhi(v), dvs, ay);
    }
    float di = dinv[i];
    unsigned int v = xwb[i * D2 + l];
    ax = fmaf(bflo(v), di, ax);
    ay = fmaf(bfhi(v), di, ay);
    float2 b2 = ((const float2*)bias)[l];
    ax = fmaf(ax, di, b2.x);
    ay = fmaf(ay, di, b2.y);
    float sum = ax + ay, sq = ax * ax + ay * ay;
    #pragma unroll
    for (int o = 32; o > 0; o >>= 1) { sum += __shfl_xor(sum, o); sq += __shfl_xor(sq, o); }
    float mu   = sum * (1.f / DD);
    float var  = sq * (1.f / DD) - mu * mu;
    float rstd = rsqrtf(var + 1e-5f);
    float2 g2  = ((const float2*)gamma)[l];
    float2 be2 = ((const float2*)beta)[l];
    float y0 = (ax - mu) * rstd * g2.x + be2.x;
    float y1 = (ay - mu) * rstd * g2.y + be2.y;
    y0 = 0.5f * y0 * (1.f + tanhf(0.7978845608f * (y0 + 0.044715f * y0 * y0 * y0)));
    y1 = 0.5f * y1 * (1.f + tanhf(0.7978845608f * (y1 + 0.044715f * y1 * y1 * y1)));
    float2 o2; o2.x = y0; o2.y = y1;
    ((float2*)out)[i * D2 + l] = o2;
}

static inline size_t align_up(size_t x, size_t a) { return (x + a - 1) & ~(a - 1); }

extern "C" void kernel_launch(void* const* d_in, const int* in_sizes, int n_in,
                              void* d_out, int out_size, void* d_ws, size_t ws_size,
                              hipStream_t stream) {
    const float* z      = (const float*)d_in[0];
    const int*   ei     = (const int*)d_in[1];
    const float* Ws     = (const float*)d_in[2];
    const float* bs     = (const float*)d_in[3];
    const float* gammas = (const float*)d_in[4];
    const float* betas  = (const float*)d_in[5];

    int E  = in_sizes[1] / 2;
    int LD = in_sizes[3];
    int Dd = in_sizes[2] / LD;            // 128
    int L  = LD / Dd;
    int N  = in_sizes[0] / Dd;
    int NB = (N + BW_DST - 1) / BW_DST;   // 313

    const int* srcp = ei;
    const int* dstp = ei + E;

    char* ws = (char*)d_ws;
    size_t off = 0;
    int* bcur = (int*)(ws + off);        off = align_up(off + (size_t)NBPAD * 4, 256);
    int* bbase = (int*)(ws + off);       off = align_up(off + (size_t)NBPAD * 4, 256);
    float* dinv = (float*)(ws + off);    off = align_up(off + (size_t)N * 4, 256);
    int* row_ptr = (int*)(ws + off);     off = align_up(off + (size_t)(N + 1) * 4, 256);
    unsigned int* bcsr = (unsigned int*)(ws + off); off = align_up(off + (size_t)NBPAD * CAP * 4, 256);
    unsigned int* csr4 = (unsigned int*)(ws + off); off = align_up(off + (size_t)E * 4, 256);
    unsigned int* xwb_a = (unsigned int*)(ws + off); off = align_up(off + (size_t)N * D2 * 4, 256);
    unsigned int* xwb_b = (unsigned int*)(ws + off); off = align_up(off + (size_t)N * D2 * 4, 256);
    float* dout = (float*)d_out;
    (void)ws_size; (void)n_in; (void)out_size;

    int nfill = (E + BATCH - 1) / BATCH;   // 157
    int nb_gemm = (N + 15) / 16;           // 625

    init_bcur<<<1, NBPAD, 0, stream>>>(bcur);
    fill_and_gemm0<<<nfill + nb_gemm, 256, 0, stream>>>(
        srcp, dstp, E, bcur, bcsr, NB, nfill, z, Ws, xwb_a, N);
    scan_cnt<<<1, 256, 0, stream>>>(bcur, bbase, row_ptr, NB, N, E);
    fine_sort<<<NB, 256, 0, stream>>>(bcur, bbase, bcsr, csr4, row_ptr, dinv, N, NB, E);

    // middle layers: fused agg(li)+LN+gelu -> GEMM W(li+1)
    unsigned int* tin = xwb_a;
    unsigned int* tout = xwb_b;
    for (int li = 0; li < L - 1; ++li) {
        agg_gemm<<<(N + 7) / 8, 512, 0, stream>>>(
            tin, csr4, row_ptr, dinv,
            bs + (size_t)li * Dd, gammas + (size_t)li * Dd, betas + (size_t)li * Dd,
            Ws + (size_t)(li + 1) * Dd * Dd, tout, N);
        unsigned int* tmp = tin; tin = tout; tout = tmp;
    }

    // final layer: agg + LN + gelu -> f32 out
    agg_ln_gelu<<<(N + 3) / 4, 256, 0, stream>>>(tin, csr4, row_ptr, dinv,
                                                 bs + (size_t)(L - 1) * Dd,
                                                 gammas + (size_t)(L - 1) * Dd,
                                                 betas + (size_t)(L - 1) * Dd, dout, N);
}